// Round 1
// baseline (510.660 us; speedup 1.0000x reference)
//
#include <hip/hip_runtime.h>
#include <math.h>

#define N_ROWS 131072
#define D_COLS 512
#define TOTAL4 (N_ROWS * D_COLS / 4)   // 16777216 float4 elements

typedef float v4f __attribute__((ext_vector_type(4)));

// Pass 1: per-thread sum / sumsq over a loop-invariant column quad.
// Compile-time trip count (templated grid) so the compiler unrolls and
// batches global loads (MLP), instead of 1-outstanding-load-per-wave.
// STRIDE is a multiple of 128 float4s, so thread t always owns columns
// 4*(g%128)..+3.
template<int NBLK>
__global__ __launch_bounds__(256)
void bn_stats_kernel(const v4f* __restrict__ X, float* __restrict__ partial) {
    constexpr int STRIDE = NBLK * 256;
    constexpr int ITERS  = TOTAL4 / STRIDE;   // exact division by construction
    const int t = threadIdx.x;
    const int g = blockIdx.x * 256 + t;

    v4f s = (v4f)0.0f;
    v4f q = (v4f)0.0f;

    #pragma unroll 8
    for (int k = 0; k < ITERS; ++k) {
        v4f x = X[g + k * STRIDE];
        s += x;
        q += x * x;
    }

    __shared__ v4f ls[256];
    __shared__ v4f lq[256];
    ls[t] = s;
    lq[t] = q;
    __syncthreads();

    // threads t and t+128 own the same column quad (g%128 equal)
    if (t < 128) {
        v4f sv = ls[t] + ls[t + 128];
        v4f qv = lq[t] + lq[t + 128];
        // layout per block: sum[512] then sumsq[512]
        float* dst = partial + (size_t)blockIdx.x * 1024;
        *(v4f*)(dst + 4 * t)       = sv;
        *(v4f*)(dst + 512 + 4 * t) = qv;
    }
}

// Pass 1b: one block per column QUAD (128 blocks). Reduce B per-block
// partials with v4f loads, emit scale[d] = gamma*rsqrt(var),
// bias[d] = beta - mean*scale.   sb layout: scale[512] then bias[512].
__global__ __launch_bounds__(256)
void bn_finalize_kernel(const float* __restrict__ partial,
                        const float* __restrict__ gamma,
                        const float* __restrict__ beta,
                        float* __restrict__ sb,
                        int B) {
    const int qd = blockIdx.x;   // 0..127
    const int t  = threadIdx.x;

    v4f s = (v4f)0.0f, q = (v4f)0.0f;
    for (int b = t; b < B; b += 256) {
        const float* src = partial + (size_t)b * 1024;
        s += *(const v4f*)(src + 4 * qd);
        q += *(const v4f*)(src + 512 + 4 * qd);
    }

    __shared__ v4f ls[256];
    __shared__ v4f lq[256];
    ls[t] = s;
    lq[t] = q;
    __syncthreads();
    for (int off = 128; off > 0; off >>= 1) {
        if (t < off) { ls[t] += ls[t + off]; lq[t] += lq[t + off]; }
        __syncthreads();
    }

    if (t == 0) {
        const float invN = 1.0f / (float)N_ROWS;
        v4f sv = ls[0], qv = lq[0];
        v4f mean = sv * invN;
        v4f var  = qv * invN - mean * mean;   // no epsilon, per reference
        v4f inv;
        inv.x = rsqrtf(var.x);
        inv.y = rsqrtf(var.y);
        inv.z = rsqrtf(var.z);
        inv.w = rsqrtf(var.w);
        v4f g4 = *(const v4f*)(gamma + 4 * qd);
        v4f b4 = *(const v4f*)(beta  + 4 * qd);
        v4f sc = g4 * inv;
        v4f bi = b4 - mean * sc;
        *(v4f*)(sb + 4 * qd)       = sc;
        *(v4f*)(sb + 512 + 4 * qd) = bi;
    }
}

// Pass 2: Y = X*scale + bias. Compile-time trip count + unroll so loads
// batch ahead of the nt stores. Y stores are non-temporal: Y is never
// re-read, and skipping cache allocation keeps X resident in L3
// (X is exactly 256 MiB = L3 size) for this pass's re-read.
template<int NBLK>
__global__ __launch_bounds__(256)
void bn_norm_kernel(const v4f* __restrict__ X,
                    v4f* __restrict__ Y,
                    const float* __restrict__ sb) {
    constexpr int STRIDE = NBLK * 256;
    constexpr int ITERS  = TOTAL4 / STRIDE;
    const int g = blockIdx.x * 256 + threadIdx.x;
    const int c = (g & 127) * 4;

    const v4f sc = *(const v4f*)(sb + c);
    const v4f bi = *(const v4f*)(sb + 512 + c);

    #pragma unroll 4
    for (int k = 0; k < ITERS; ++k) {
        v4f x = X[g + k * STRIDE];
        v4f y = x * sc + bi;
        __builtin_nontemporal_store(y, &Y[g + k * STRIDE]);
    }
}

extern "C" void kernel_launch(void* const* d_in, const int* in_sizes, int n_in,
                              void* d_out, int out_size, void* d_ws, size_t ws_size,
                              hipStream_t stream) {
    const float* X     = (const float*)d_in[0];
    const float* gamma = (const float*)d_in[1];
    const float* beta  = (const float*)d_in[2];
    float* Y  = (float*)d_out;
    float* ws = (float*)d_ws;

    // Preferred: 2048 stats blocks -> 8 MiB of partials + 4 KiB scale/bias.
    int B = 2048;
    if (((size_t)B * 1024 + 1024) * sizeof(float) > ws_size) B = 512;

    float* partial = ws;
    float* sb      = ws + (size_t)B * 1024;   // scale[512] then bias[512]

    if (B == 2048) {
        bn_stats_kernel<2048><<<2048, 256, 0, stream>>>((const v4f*)X, partial);
    } else {
        bn_stats_kernel<512><<<512, 256, 0, stream>>>((const v4f*)X, partial);
    }
    bn_finalize_kernel<<<128, 256, 0, stream>>>(partial, gamma, beta, sb, B);
    bn_norm_kernel<4096><<<4096, 256, 0, stream>>>((const v4f*)X, (v4f*)Y, sb);
}